// Round 14
// baseline (4076.591 us; speedup 1.0000x reference)
//
#include <hip/hip_runtime.h>
#include <hip/hip_bf16.h>
#include <hip/hip_cooperative_groups.h>

namespace cg = cooperative_groups;

// ---------------------------------------------------------------------------
// SGCN: 3 x [GEMM -> normalized SpMM (+self loop) -> bias+ReLU] -> mean pool
//       -> linear classifier.
// R3: LDS-aggregated CSR build (global atomics are memory-side RMWs).
// R5: gemm thread=node, acc[64] in VGPRs, W broadcast from LDS.
// R6-R12: spmm pinned at 118us/400MB L2-miss traffic; compulsory floor
//     ~230MB (8 XCDs x 25.6MB + cpair + OUT). Passive co-phasing failed
//     (R11); GEMM-fusion stretched critical path (R13: 145 vs 118).
// R13(this): COOPERATIVE co-phased spmm8: 1280 blocks all-resident, each
//     owns 79 dst nodes with LDS accumulators; tiles t=0..6 swept with
//     grid.sync() between -> whole chip gathers from one 4MB tile at a
//     time (L2-resident per XCD) -> capacity misses eliminated.
//     Build = R11's proven tiled-rowseg kernels. Fusion dropped.
// ---------------------------------------------------------------------------

#define WS_ALIGN(x) (((x) + 255) & ~(size_t)255)
#define POOL_CHUNK 128
#define ECHUNK 8192                    // edges per build block
#define BSHIFT 5                       // 32 dst nodes per bucket
#define BMASK  ((1 << BSHIFT) - 1)
#define SRCBITS 17                     // N=100000 < 2^17
#define BCAP 1280                      // bucket capacity (mean 1024 + 8 sigma)
#define TILE_SHIFT 14                  // 16384 srcs per tile = 4MB = L2
#define NTILE 7                        // ceil(100000 / 16384)
#define CGRID 1280                     // cooperative grid (5 blocks/CU)
#define NPB   79                       // nodes per block; CGRID*NPB >= N

typedef float f32x4 __attribute__((ext_vector_type(4)));

// ---- build 1: scatter edges into padded bucket regions --------------------
__global__ __launch_bounds__(512)
void scatterD_kernel(const int* __restrict__ src, const int* __restrict__ dst,
                     const float* __restrict__ ea, int E, int NB,
                     int* __restrict__ bcursor, int2* __restrict__ sbuf) {
    extern __shared__ int sh[];
    for (int i = threadIdx.x; i < NB; i += 512) sh[i] = 0;
    __syncthreads();
    int beg = blockIdx.x * ECHUNK, end = min(beg + ECHUNK, E);
    for (int i = beg + threadIdx.x; i < end; i += 512)
        atomicAdd(&sh[dst[i] >> BSHIFT], 1);
    __syncthreads();
    for (int i = threadIdx.x; i < NB; i += 512) {
        int c = sh[i];
        sh[i] = c ? (i * BCAP + atomicAdd(&bcursor[i], c)) : 0;
    }
    __syncthreads();
    for (int i = beg + threadIdx.x; i < end; i += 512) {
        int s = src[i], d = dst[i];
        int pos = atomicAdd(&sh[d >> BSHIFT], 1);        // LDS cursor
        sbuf[pos] = make_int2(s | ((d & BMASK) << SRCBITS),
                              __float_as_int(ea[i]));
    }
}

// ---- build 2: per-(dst,tile) counts -> dinv + tile-segmented rowseg -------
__global__ __launch_bounds__(256)
void bucketE1_kernel(const int2* __restrict__ sbuf, const int* __restrict__ bcnt,
                     int N, float* __restrict__ dinv, int* __restrict__ rowseg) {
    __shared__ int scnt[32 * 8];
    for (int i = threadIdx.x; i < 32 * 8; i += 256) scnt[i] = 0;
    __syncthreads();
    int b = blockIdx.x;
    int base = b * BCAP, cnt = bcnt[b];
    for (int j = threadIdx.x; j < cnt; j += 256) {
        int2 e = sbuf[base + j];
        int dl = (e.x >> SRCBITS) & BMASK;
        int t  = (e.x & ((1 << SRCBITS) - 1)) >> TILE_SHIFT;
        atomicAdd(&scnt[dl * 8 + t], 1);
    }
    __syncthreads();
    if (threadIdx.x < 32) {
        int dl = threadIdx.x;
        int deg = 0;
        #pragma unroll
        for (int t = 0; t < NTILE; ++t) deg += scnt[dl * 8 + t];
        int x = deg;                                     // wave prefix
        #pragma unroll
        for (int off = 1; off < 32; off <<= 1) {
            int tt = __shfl_up(x, off);
            if (dl >= off) x += tt;
        }
        int rb = base + x - deg;                         // row start
        int d = (b << BSHIFT) + dl;
        if (d < N) {
            dinv[d] = 1.0f / sqrtf((float)(deg + 1));    // +1 = self loop
            int* rs = rowseg + (size_t)d * 8;
            int off = rb;
            #pragma unroll
            for (int t = 0; t < NTILE; ++t) { rs[t] = off; off += scnt[dl * 8 + t]; }
            rs[NTILE] = off;                             // row end (slot 7)
        }
    }
}

// ---- build 3: scatter to cpair (cursors from rowseg; dinv fully written) --
__global__ __launch_bounds__(256)
void bucketE2_kernel(const int2* __restrict__ sbuf, const int* __restrict__ bcnt,
                     const float* __restrict__ dinv, int N,
                     const int* __restrict__ rowseg, int2* __restrict__ cpair) {
    __shared__ int scur[32 * 8];
    __shared__ float sdinv[32];
    int b = blockIdx.x;
    int dbase = b << BSHIFT;
    for (int i = threadIdx.x; i < 32 * 8; i += 256) {
        int dl = i >> 3, t = i & 7;
        int d = dbase + dl;
        scur[i] = (d < N && t < NTILE) ? rowseg[(size_t)d * 8 + t] : 0;
    }
    if (threadIdx.x < 32) {
        int d = dbase + threadIdx.x;
        sdinv[threadIdx.x] = (d < N) ? dinv[d] : 0.f;
    }
    __syncthreads();
    int base = b * BCAP, cnt = bcnt[b];
    for (int j = threadIdx.x; j < cnt; j += 256) {
        int2 e = sbuf[base + j];
        int dl = (e.x >> SRCBITS) & BMASK;
        int s  = e.x & ((1 << SRCBITS) - 1);
        float c = dinv[s] * sdinv[dl] * expf(-__int_as_float(e.y));
        int pos = atomicAdd(&scur[dl * 8 + (s >> TILE_SHIFT)], 1);
        cpair[pos] = make_int2(s, __float_as_int(c));
    }
}

// ---- dense GEMM: Y[N,64] = X[N,K] @ W[K,64] --------------------------------
template <int K>
__global__ __launch_bounds__(256)
void gemm3_kernel(const float* __restrict__ X, const float* __restrict__ W,
                  float* __restrict__ Y, int N) {
    __shared__ float sW[K * 64];
    for (int i = threadIdx.x; i < K * 64; i += 256) sW[i] = W[i];
    __syncthreads();
    int node = blockIdx.x * 256 + threadIdx.x;
    if (node >= N) return;
    const float4* xr = reinterpret_cast<const float4*>(X + (size_t)node * K);
    float acc[64];
    #pragma unroll
    for (int c = 0; c < 64; ++c) acc[c] = 0.f;
    #pragma unroll 2
    for (int k4 = 0; k4 < K / 4; ++k4) {
        float4 xv = xr[k4];
        #pragma unroll
        for (int j = 0; j < 4; ++j) {
            float xs = (j == 0) ? xv.x : (j == 1) ? xv.y : (j == 2) ? xv.z : xv.w;
            const float4* wr =
                reinterpret_cast<const float4*>(sW + (k4 * 4 + j) * 64);
            #pragma unroll
            for (int c4 = 0; c4 < 16; ++c4) {
                float4 wv = wr[c4];
                acc[4 * c4 + 0] = fmaf(xs, wv.x, acc[4 * c4 + 0]);
                acc[4 * c4 + 1] = fmaf(xs, wv.y, acc[4 * c4 + 1]);
                acc[4 * c4 + 2] = fmaf(xs, wv.z, acc[4 * c4 + 2]);
                acc[4 * c4 + 3] = fmaf(xs, wv.w, acc[4 * c4 + 3]);
            }
        }
    }
    float4* yr = reinterpret_cast<float4*>(Y + (size_t)node * 64);
    #pragma unroll
    for (int c4 = 0; c4 < 16; ++c4)
        yr[c4] = make_float4(acc[4 * c4 + 0], acc[4 * c4 + 1],
                             acc[4 * c4 + 2], acc[4 * c4 + 3]);
}

// ---- SpMM common: one edge's contribution to a float4 of channels ---------
__device__ __forceinline__ void quad_acc(const int2* __restrict__ cpair,
                                         int eidx, const float* __restrict__ HW,
                                         int chb, float4& acc, bool ok) {
    long long pv = __builtin_nontemporal_load(
        reinterpret_cast<const long long*>(cpair) + eidx);
    int   s = (int)(pv & 0xffffffffLL);
    float c = __int_as_float((int)(pv >> 32));
    c = ok ? c : 0.f;
    const float4 hv = *reinterpret_cast<const float4*>(
        HW + (size_t)s * 64 + chb);
    acc.x = fmaf(c, hv.x, acc.x);
    acc.y = fmaf(c, hv.y, acc.y);
    acc.z = fmaf(c, hv.z, acc.z);
    acc.w = fmaf(c, hv.w, acc.w);
}

// ---- SpMM v8: cooperative co-phased src-tile sweep ------------------------
// 1280 all-resident blocks; block owns nodes [b*NPB, b*NPB+NPB); LDS acc.
// Phase t: every block gathers only from src tile t (4MB, L2-resident);
// grid.sync() between phases. Self-loop added during the owning tile.
__global__ __launch_bounds__(256, 5)
void spmm8_kernel(const float* __restrict__ HW,
                  const int* __restrict__ rowseg,
                  const int2* __restrict__ cpair,
                  const float* __restrict__ dinv,
                  const float* __restrict__ bias,
                  float* __restrict__ OUT, int N) {
    cg::grid_group grid = cg::this_grid();
    __shared__ float acc[NPB][64];
    const int lane = threadIdx.x & 63, wid = threadIdx.x >> 6;
    const int g = lane >> 4, chb = (lane & 15) * 4;
    const int base = blockIdx.x * NPB;

    // init own nodes' acc (wave w owns nl = w, w+4, ...)
    for (int nl = wid; nl < NPB; nl += 4)
        if (lane < 16)
            *reinterpret_cast<float4*>(&acc[nl][chb]) =
                make_float4(0.f, 0.f, 0.f, 0.f);

    #pragma unroll
    for (int t = 0; t < NTILE; ++t) {
        for (int nl = wid; nl < NPB; nl += 4) {
            int node = base + nl;
            if (node >= N) break;
            int sbeg = rowseg[(size_t)node * 8 + t];
            int send = rowseg[(size_t)node * 8 + t + 1];
            bool self = (t == (node >> TILE_SHIFT));
            if (sbeg == send && !self) continue;
            float4 a0 = make_float4(0.f, 0.f, 0.f, 0.f);
            for (int j = sbeg; j < send; j += 4) {
                int e = j + g;
                bool ok = e < send;
                quad_acc(cpair, ok ? e : sbeg, HW, chb, a0, ok);
            }
            a0.x += __shfl_xor(a0.x, 32); a0.y += __shfl_xor(a0.y, 32);
            a0.z += __shfl_xor(a0.z, 32); a0.w += __shfl_xor(a0.w, 32);
            a0.x += __shfl_xor(a0.x, 16); a0.y += __shfl_xor(a0.y, 16);
            a0.z += __shfl_xor(a0.z, 16); a0.w += __shfl_xor(a0.w, 16);
            if (lane < 16) {
                if (self) {
                    float di = dinv[node];
                    float s2 = di * di;
                    const float4 hs = *reinterpret_cast<const float4*>(
                        HW + (size_t)node * 64 + chb);
                    a0.x = fmaf(s2, hs.x, a0.x);
                    a0.y = fmaf(s2, hs.y, a0.y);
                    a0.z = fmaf(s2, hs.z, a0.z);
                    a0.w = fmaf(s2, hs.w, a0.w);
                }
                float4 cur = *reinterpret_cast<float4*>(&acc[nl][chb]);
                cur.x += a0.x; cur.y += a0.y; cur.z += a0.z; cur.w += a0.w;
                *reinterpret_cast<float4*>(&acc[nl][chb]) = cur;
            }
        }
        if (t + 1 < NTILE) grid.sync();
    }

    // epilogue: bias + relu + NT store (per-wave own nodes; no barrier needed)
    for (int nl = wid; nl < NPB; nl += 4) {
        int node = base + nl;
        if (node >= N) break;
        if (lane < 16) {
            float4 r  = *reinterpret_cast<float4*>(&acc[nl][chb]);
            float4 bv = *reinterpret_cast<const float4*>(bias + chb);
            f32x4 o;
            o.x = fmaxf(r.x + bv.x, 0.f);
            o.y = fmaxf(r.y + bv.y, 0.f);
            o.z = fmaxf(r.z + bv.z, 0.f);
            o.w = fmaxf(r.w + bv.w, 0.f);
            __builtin_nontemporal_store(o, reinterpret_cast<f32x4*>(
                OUT + (size_t)node * 64 + chb));
        }
    }
}

// ---- pool stage 1: per-chunk per-graph partial sums -----------------------
__global__ __launch_bounds__(256)
void pool1_kernel(const float* __restrict__ H, const int* __restrict__ batch,
                  int N, int B, float* __restrict__ partial) {
    __shared__ float part[4][16][64];
    int lane = threadIdx.x & 63, wid = threadIdx.x >> 6;
    for (int g = 0; g < 16; ++g) part[wid][g][lane] = 0.f;
    int beg = blockIdx.x * POOL_CHUNK;
    int end = min(beg + POOL_CHUNK, N);
    float acc = 0.f; int cur = -1;
    for (int v = beg + wid; v < end; v += 4) {
        int g = batch[v];
        if (g != cur) {
            if (cur >= 0) part[wid][cur][lane] += acc;
            cur = g; acc = 0.f;
        }
        acc += H[(size_t)v * 64 + lane];
    }
    if (cur >= 0) part[wid][cur][lane] += acc;
    __syncthreads();
    float* outp = partial + (size_t)blockIdx.x * B * 64;
    for (int idx = threadIdx.x; idx < B * 64; idx += 256) {
        int g = idx >> 6, l = idx & 63;
        outp[idx] = part[0][g][l] + part[1][g][l] + part[2][g][l] + part[3][g][l];
    }
}

// ---- pool stage 2: fixed-order reduce over blocks, divide by count --------
__global__ __launch_bounds__(256)
void pool2_kernel(const float* __restrict__ partial, int nblk, int B,
                  const int* __restrict__ batch, int N,
                  float* __restrict__ pooled) {
    int g = blockIdx.x;
    int lane = threadIdx.x & 63, wid = threadIdx.x >> 6;
    float acc = 0.f;
    for (int b = wid; b < nblk; b += 4)
        acc += partial[(size_t)b * B * 64 + g * 64 + lane];
    __shared__ float sacc[4][64];
    sacc[wid][lane] = acc;
    __syncthreads();
    if (wid == 0) {
        int lo = 0, hi = N;
        while (lo < hi) { int m = (lo + hi) >> 1; if (batch[m] < g) lo = m + 1; else hi = m; }
        int s0 = lo;
        lo = 0; hi = N;
        while (lo < hi) { int m = (lo + hi) >> 1; if (batch[m] < g + 1) lo = m + 1; else hi = m; }
        float cnt = (float)(lo - s0);
        float s = sacc[0][lane] + sacc[1][lane] + sacc[2][lane] + sacc[3][lane];
        pooled[g * 64 + lane] = s / fmaxf(cnt, 1.0f);
    }
}

// ---- classifier: out[B,C] = pooled[B,64] @ Wc[64,C] + bc ------------------
__global__ __launch_bounds__(256)
void final_kernel(const float* __restrict__ pooled, const float* __restrict__ Wc,
                  const float* __restrict__ bc, float* __restrict__ out, int C) {
    int b = blockIdx.x;
    __shared__ float sp[64];
    if (threadIdx.x < 64) sp[threadIdx.x] = pooled[b * 64 + threadIdx.x];
    __syncthreads();
    for (int c = threadIdx.x; c < C; c += blockDim.x) {
        float acc = bc[c];
        #pragma unroll
        for (int k = 0; k < 64; ++k) acc = fmaf(sp[k], Wc[k * C + c], acc);
        out[b * C + c] = acc;
    }
}

extern "C" void kernel_launch(void* const* d_in, const int* in_sizes, int n_in,
                              void* d_out, int out_size, void* d_ws, size_t ws_size,
                              hipStream_t stream) {
    const float* x     = (const float*)d_in[0];
    const int*   esrc  = (const int*)  d_in[1];
    const int*   edst  = (const int*)  d_in[2];
    const float* ea    = (const float*)d_in[3];
    const int*   batch = (const int*)  d_in[4];
    const float* W0 = (const float*)d_in[5];  const float* b0 = (const float*)d_in[6];
    const float* W1 = (const float*)d_in[7];  const float* b1 = (const float*)d_in[8];
    const float* W2 = (const float*)d_in[9];  const float* b2 = (const float*)d_in[10];
    const float* Wc = (const float*)d_in[11]; const float* bc = (const float*)d_in[12];

    const int N = in_sizes[4];
    const int E = in_sizes[1];
    const int C = in_sizes[12];            // 196
    const int B = out_size / C;            // 16
    (void)n_in; (void)ws_size;

    const int NB        = (N + BMASK) >> BSHIFT;              // dst buckets
    const int nchunk    = (E + ECHUNK - 1) / ECHUNK;          // build chunks
    const int nblk_pool = (N + POOL_CHUNK - 1) / POOL_CHUNK;
    const size_t PADDED = (size_t)NB * BCAP;                  // padded entries

    // ---- carve workspace ----
    char* w = (char*)d_ws;
    auto alloc = [&](size_t bytes) { void* p = (void*)w; w += WS_ALIGN(bytes); return p; };
    float* d_dinv    = (float*)alloc((size_t)N * 4);
    int*   d_rowseg  = (int*)  alloc((size_t)N * 8 * 4);
    int*   d_bcursor = (int*)  alloc((size_t)NB * 4);
    int2*  d_cpair   = (int2*) alloc(PADDED * 8);
    float* d_hA      = (float*)alloc((size_t)N * 64 * 4);
    size_t tmp_bytes = (size_t)N * 64 * 4;
    if (PADDED * 8 > tmp_bytes) tmp_bytes = PADDED * 8;
    float* d_tmp     = (float*)alloc(tmp_bytes);
    float* d_partial = (float*)alloc((size_t)nblk_pool * B * 64 * 4);
    float* d_pool    = (float*)alloc((size_t)B * 64 * 4);
    int2*  d_sbuf    = (int2*)d_tmp;   // alias: staging dead before first gemm

    // ---- build CSR (padded buckets, tile-segmented rows; R11-proven) ----
    hipMemsetAsync(d_bcursor, 0, (size_t)NB * 4, stream);
    scatterD_kernel<<<nchunk, 512, NB * 4, stream>>>(esrc, edst, ea, E, NB,
                                                     d_bcursor, d_sbuf);
    bucketE1_kernel<<<NB, 256, 0, stream>>>(d_sbuf, d_bcursor, N, d_dinv, d_rowseg);
    bucketE2_kernel<<<NB, 256, 0, stream>>>(d_sbuf, d_bcursor, d_dinv, N,
                                            d_rowseg, d_cpair);

    auto launch_spmm = [&](const float* in, const float* bias, float* out) {
        const float* hw = in; const int* rs = d_rowseg; const int2* cp = d_cpair;
        const float* dv = d_dinv; const float* bs = bias; float* o = out; int n = N;
        void* args[] = {(void*)&hw, (void*)&rs, (void*)&cp, (void*)&dv,
                        (void*)&bs, (void*)&o, (void*)&n};
        hipLaunchCooperativeKernel((const void*)spmm8_kernel, dim3(CGRID),
                                   dim3(256), args, 0u, stream);
    };

    const int gblk = (N + 255) / 256;
    // ---- layer 0 (K=128) ----
    gemm3_kernel<128><<<gblk, 256, 0, stream>>>(x, W0, d_tmp, N);
    launch_spmm(d_tmp, b0, d_hA);
    // ---- layer 1 (K=64) ----
    gemm3_kernel<64><<<gblk, 256, 0, stream>>>(d_hA, W1, d_tmp, N);
    launch_spmm(d_tmp, b1, d_hA);
    // ---- layer 2 (K=64) ----
    gemm3_kernel<64><<<gblk, 256, 0, stream>>>(d_hA, W2, d_tmp, N);
    launch_spmm(d_tmp, b2, d_hA);

    // ---- pool + classifier ----
    pool1_kernel<<<nblk_pool, 256, 0, stream>>>(d_hA, batch, N, B, d_partial);
    pool2_kernel<<<B, 256, 0, stream>>>(d_partial, nblk_pool, B, batch, N, d_pool);
    final_kernel<<<B, 256, 0, stream>>>(d_pool, Wc, bc, (float*)d_out, C);
}

// Round 15
// 628.982 us; speedup vs baseline: 6.4812x; 6.4812x over previous
//
#include <hip/hip_runtime.h>
#include <hip/hip_bf16.h>

// ---------------------------------------------------------------------------
// SGCN: 3 x [GEMM -> normalized SpMM (+self loop) -> bias+ReLU] -> mean pool
//       -> linear classifier.
// CSR built once (padded dst-buckets), reused 3 layers.
// R3: LDS-aggregated build (global atomics are memory-side RMWs on gfx950).
// R5: gemm thread=node, acc[64] in VGPRs, W broadcast from LDS.
// R6-R14: spmm traffic/latency study: full-sweep = 400MB @3.4TB/s (118us);
//     channel-split, src-tiling, GEMM-fusion, cooperative co-phasing all
//     falsified (co-phase hit the 180MB compulsory floor but dropped to
//     164GB/s -- MLP destroyed by 4.6-edge segments). spmm4 full-row is
//     the structure; this round tests 4-acc unroll (MLP) as the last lever.
// R14: (a) revert to R10-best; (b) spmm4 16-edge/4-acc main loop;
//     (c) scatterD ECHUNK 16384 (halves partial-line write amplification).
// ---------------------------------------------------------------------------

#define WS_ALIGN(x) (((x) + 255) & ~(size_t)255)
#define POOL_CHUNK 128
#define ECHUNK 16384                   // edges per build block (R14: was 8192)
#define BSHIFT 5                       // 32 dst nodes per bucket
#define BMASK  ((1 << BSHIFT) - 1)
#define SRCBITS 17                     // N=100000 < 2^17
#define BCAP 1280                      // bucket capacity (mean 1024 + 8 sigma)

typedef float f32x4 __attribute__((ext_vector_type(4)));

// ---- build 1: scatter edges into padded bucket regions --------------------
__global__ __launch_bounds__(512)
void scatterD_kernel(const int* __restrict__ src, const int* __restrict__ dst,
                     const float* __restrict__ ea, int E, int NB,
                     int* __restrict__ bcursor, int2* __restrict__ sbuf) {
    extern __shared__ int sh[];
    for (int i = threadIdx.x; i < NB; i += 512) sh[i] = 0;
    __syncthreads();
    int beg = blockIdx.x * ECHUNK, end = min(beg + ECHUNK, E);
    for (int i = beg + threadIdx.x; i < end; i += 512)
        atomicAdd(&sh[dst[i] >> BSHIFT], 1);
    __syncthreads();
    for (int i = threadIdx.x; i < NB; i += 512) {
        int c = sh[i];
        sh[i] = c ? (i * BCAP + atomicAdd(&bcursor[i], c)) : 0;
    }
    __syncthreads();
    for (int i = beg + threadIdx.x; i < end; i += 512) {
        int s = src[i], d = dst[i];
        int pos = atomicAdd(&sh[d >> BSHIFT], 1);        // LDS cursor
        sbuf[pos] = make_int2(s | ((d & BMASK) << SRCBITS),
                              __float_as_int(ea[i]));
    }
}

// ---- build 2: per-bucket degree count -> dinv, rowbeg/rowend --------------
__global__ __launch_bounds__(256)
void bucketE1_kernel(const int2* __restrict__ sbuf, const int* __restrict__ bcnt,
                     int N, float* __restrict__ dinv,
                     int* __restrict__ rowbeg, int* __restrict__ rowend) {
    __shared__ int dcount[32];
    if (threadIdx.x < 32) dcount[threadIdx.x] = 0;
    __syncthreads();
    int b = blockIdx.x;
    int base = b * BCAP, cnt = bcnt[b];
    for (int j = threadIdx.x; j < cnt; j += 256)
        atomicAdd(&dcount[(sbuf[base + j].x >> SRCBITS) & BMASK], 1);
    __syncthreads();
    if (threadIdx.x < 32) {
        int c = dcount[threadIdx.x];
        int x = c;
        #pragma unroll
        for (int off = 1; off < 32; off <<= 1) {
            int t = __shfl_up(x, off);
            if (threadIdx.x >= off) x += t;
        }
        int d = (b << BSHIFT) + threadIdx.x;
        if (d < N) {
            int rb = base + x - c;                       // exclusive prefix
            rowbeg[d] = rb;
            rowend[d] = rb + c;
            dinv[d]   = 1.0f / sqrtf((float)(c + 1));    // +1 = self loop
        }
    }
}

// ---- build 3: within-bucket scatter to final CSR + coefficient ------------
__global__ __launch_bounds__(256)
void bucketE2_kernel(const int2* __restrict__ sbuf, const int* __restrict__ bcnt,
                     const float* __restrict__ dinv, int N,
                     const int* __restrict__ rowbeg, int2* __restrict__ cpair) {
    __shared__ int cur[32];
    __shared__ float sdinv[32];
    int b = blockIdx.x;
    int dbase = b << BSHIFT;
    if (threadIdx.x < 32) {
        int d = dbase + threadIdx.x;
        cur[threadIdx.x]   = (d < N) ? rowbeg[d] : 0;
        sdinv[threadIdx.x] = (d < N) ? dinv[d] : 0.f;
    }
    __syncthreads();
    int base = b * BCAP, cnt = bcnt[b];
    for (int j = threadIdx.x; j < cnt; j += 256) {
        int2 e = sbuf[base + j];
        int dl = (e.x >> SRCBITS) & BMASK;
        int s  = e.x & ((1 << SRCBITS) - 1);
        float c = dinv[s] * sdinv[dl] * expf(-__int_as_float(e.y));
        int pos = atomicAdd(&cur[dl], 1);                // LDS cursor
        cpair[pos] = make_int2(s, __float_as_int(c));
    }
}

// ---- dense GEMM: Y[N,64] = X[N,K] @ W[K,64] --------------------------------
// thread = node; acc[64] static in VGPRs; W broadcast from LDS (b128).
template <int K>
__global__ __launch_bounds__(256)
void gemm3_kernel(const float* __restrict__ X, const float* __restrict__ W,
                  float* __restrict__ Y, int N) {
    __shared__ float sW[K * 64];
    for (int i = threadIdx.x; i < K * 64; i += 256) sW[i] = W[i];
    __syncthreads();
    int node = blockIdx.x * 256 + threadIdx.x;
    if (node >= N) return;
    const float4* xr = reinterpret_cast<const float4*>(X + (size_t)node * K);
    float acc[64];
    #pragma unroll
    for (int c = 0; c < 64; ++c) acc[c] = 0.f;
    #pragma unroll 2
    for (int k4 = 0; k4 < K / 4; ++k4) {
        float4 xv = xr[k4];
        #pragma unroll
        for (int j = 0; j < 4; ++j) {
            float xs = (j == 0) ? xv.x : (j == 1) ? xv.y : (j == 2) ? xv.z : xv.w;
            const float4* wr =
                reinterpret_cast<const float4*>(sW + (k4 * 4 + j) * 64);
            #pragma unroll
            for (int c4 = 0; c4 < 16; ++c4) {
                float4 wv = wr[c4];
                acc[4 * c4 + 0] = fmaf(xs, wv.x, acc[4 * c4 + 0]);
                acc[4 * c4 + 1] = fmaf(xs, wv.y, acc[4 * c4 + 1]);
                acc[4 * c4 + 2] = fmaf(xs, wv.z, acc[4 * c4 + 2]);
                acc[4 * c4 + 3] = fmaf(xs, wv.w, acc[4 * c4 + 3]);
            }
        }
    }
    float4* yr = reinterpret_cast<float4*>(Y + (size_t)node * 64);
    #pragma unroll
    for (int c4 = 0; c4 < 16; ++c4)
        yr[c4] = make_float4(acc[4 * c4 + 0], acc[4 * c4 + 1],
                             acc[4 * c4 + 2], acc[4 * c4 + 3]);
}

// ---- SpMM common: one edge's contribution to a float4 of channels ---------
__device__ __forceinline__ void quad_acc(const int2* __restrict__ cpair,
                                         int eidx, const float* __restrict__ HW,
                                         int chb, float4& acc, bool ok) {
    long long pv = __builtin_nontemporal_load(
        reinterpret_cast<const long long*>(cpair) + eidx);
    int   s = (int)(pv & 0xffffffffLL);
    float c = __int_as_float((int)(pv >> 32));
    c = ok ? c : 0.f;
    const float4 hv = *reinterpret_cast<const float4*>(
        HW + (size_t)s * 64 + chb);
    acc.x = fmaf(c, hv.x, acc.x);
    acc.y = fmaf(c, hv.y, acc.y);
    acc.z = fmaf(c, hv.z, acc.z);
    acc.w = fmaf(c, hv.w, acc.w);
}

// ---- SpMM v4u: lane = (edge-slot 0..3, chan-quad 0..15); 4-acc unroll -----
// R14: 16 edges (4 independent vmem chains) in flight per wave.
__global__ __launch_bounds__(256)
void spmm4_kernel(const float* __restrict__ HW,
                  const int* __restrict__ rowbeg,
                  const int* __restrict__ rowend,
                  const int2* __restrict__ cpair,
                  const float* __restrict__ dinv,
                  const float* __restrict__ bias,
                  float* __restrict__ OUT, int N) {
    int node = blockIdx.x * 4 + (threadIdx.x >> 6);
    if (node >= N) return;
    int lane = threadIdx.x & 63;
    int g    = lane >> 4;              // edge slot
    int chb  = (lane & 15) * 4;        // channel base (float4)
    int beg = rowbeg[node], end = rowend[node];
    float di = dinv[node];

    float4 a0 = make_float4(0.f, 0.f, 0.f, 0.f);
    float4 a1 = make_float4(0.f, 0.f, 0.f, 0.f);
    float4 a2 = make_float4(0.f, 0.f, 0.f, 0.f);
    float4 a3 = make_float4(0.f, 0.f, 0.f, 0.f);
    float4 hs = *reinterpret_cast<const float4*>(HW + (size_t)node * 64 + chb);
    if (g == 0) {
        float s2 = di * di;
        a0 = make_float4(s2 * hs.x, s2 * hs.y, s2 * hs.z, s2 * hs.w);
    }

    int j = beg;
    for (; j + 16 <= end; j += 16) {
        quad_acc(cpair, j + g,      HW, chb, a0, true);
        quad_acc(cpair, j + 4 + g,  HW, chb, a1, true);
        quad_acc(cpair, j + 8 + g,  HW, chb, a2, true);
        quad_acc(cpair, j + 12 + g, HW, chb, a3, true);
    }
    for (; j + 8 <= end; j += 8) {
        quad_acc(cpair, j + g,     HW, chb, a0, true);
        quad_acc(cpair, j + 4 + g, HW, chb, a1, true);
    }
    for (; j < end; j += 4) {
        int e = j + g;
        bool ok = e < end;
        quad_acc(cpair, ok ? e : beg, HW, chb, a0, ok);
    }

    float4 r = make_float4((a0.x + a1.x) + (a2.x + a3.x),
                           (a0.y + a1.y) + (a2.y + a3.y),
                           (a0.z + a1.z) + (a2.z + a3.z),
                           (a0.w + a1.w) + (a2.w + a3.w));
    r.x += __shfl_xor(r.x, 32); r.y += __shfl_xor(r.y, 32);
    r.z += __shfl_xor(r.z, 32); r.w += __shfl_xor(r.w, 32);
    r.x += __shfl_xor(r.x, 16); r.y += __shfl_xor(r.y, 16);
    r.z += __shfl_xor(r.z, 16); r.w += __shfl_xor(r.w, 16);

    if (lane < 16) {
        float4 bv = *reinterpret_cast<const float4*>(bias + chb);
        f32x4 o;
        o.x = fmaxf(r.x + bv.x, 0.f);
        o.y = fmaxf(r.y + bv.y, 0.f);
        o.z = fmaxf(r.z + bv.z, 0.f);
        o.w = fmaxf(r.w + bv.w, 0.f);
        __builtin_nontemporal_store(o, reinterpret_cast<f32x4*>(
            OUT + (size_t)node * 64 + chb));
    }
}

// ---- pool stage 1: per-chunk per-graph partial sums -----------------------
__global__ __launch_bounds__(256)
void pool1_kernel(const float* __restrict__ H, const int* __restrict__ batch,
                  int N, int B, float* __restrict__ partial) {
    __shared__ float part[4][16][64];
    int lane = threadIdx.x & 63, wid = threadIdx.x >> 6;
    for (int g = 0; g < 16; ++g) part[wid][g][lane] = 0.f;
    int beg = blockIdx.x * POOL_CHUNK;
    int end = min(beg + POOL_CHUNK, N);
    float acc = 0.f; int cur = -1;
    for (int v = beg + wid; v < end; v += 4) {
        int g = batch[v];
        if (g != cur) {
            if (cur >= 0) part[wid][cur][lane] += acc;
            cur = g; acc = 0.f;
        }
        acc += H[(size_t)v * 64 + lane];
    }
    if (cur >= 0) part[wid][cur][lane] += acc;
    __syncthreads();
    float* outp = partial + (size_t)blockIdx.x * B * 64;
    for (int idx = threadIdx.x; idx < B * 64; idx += 256) {
        int g = idx >> 6, l = idx & 63;
        outp[idx] = part[0][g][l] + part[1][g][l] + part[2][g][l] + part[3][g][l];
    }
}

// ---- pool stage 2: fixed-order reduce over blocks, divide by count --------
__global__ __launch_bounds__(256)
void pool2_kernel(const float* __restrict__ partial, int nblk, int B,
                  const int* __restrict__ batch, int N,
                  float* __restrict__ pooled) {
    int g = blockIdx.x;
    int lane = threadIdx.x & 63, wid = threadIdx.x >> 6;
    float acc = 0.f;
    for (int b = wid; b < nblk; b += 4)
        acc += partial[(size_t)b * B * 64 + g * 64 + lane];
    __shared__ float sacc[4][64];
    sacc[wid][lane] = acc;
    __syncthreads();
    if (wid == 0) {
        int lo = 0, hi = N;
        while (lo < hi) { int m = (lo + hi) >> 1; if (batch[m] < g) lo = m + 1; else hi = m; }
        int s0 = lo;
        lo = 0; hi = N;
        while (lo < hi) { int m = (lo + hi) >> 1; if (batch[m] < g + 1) lo = m + 1; else hi = m; }
        float cnt = (float)(lo - s0);
        float s = sacc[0][lane] + sacc[1][lane] + sacc[2][lane] + sacc[3][lane];
        pooled[g * 64 + lane] = s / fmaxf(cnt, 1.0f);
    }
}

// ---- classifier: out[B,C] = pooled[B,64] @ Wc[64,C] + bc ------------------
__global__ __launch_bounds__(256)
void final_kernel(const float* __restrict__ pooled, const float* __restrict__ Wc,
                  const float* __restrict__ bc, float* __restrict__ out, int C) {
    int b = blockIdx.x;
    __shared__ float sp[64];
    if (threadIdx.x < 64) sp[threadIdx.x] = pooled[b * 64 + threadIdx.x];
    __syncthreads();
    for (int c = threadIdx.x; c < C; c += blockDim.x) {
        float acc = bc[c];
        #pragma unroll
        for (int k = 0; k < 64; ++k) acc = fmaf(sp[k], Wc[k * C + c], acc);
        out[b * C + c] = acc;
    }
}

extern "C" void kernel_launch(void* const* d_in, const int* in_sizes, int n_in,
                              void* d_out, int out_size, void* d_ws, size_t ws_size,
                              hipStream_t stream) {
    const float* x     = (const float*)d_in[0];
    const int*   esrc  = (const int*)  d_in[1];
    const int*   edst  = (const int*)  d_in[2];
    const float* ea    = (const float*)d_in[3];
    const int*   batch = (const int*)  d_in[4];
    const float* W0 = (const float*)d_in[5];  const float* b0 = (const float*)d_in[6];
    const float* W1 = (const float*)d_in[7];  const float* b1 = (const float*)d_in[8];
    const float* W2 = (const float*)d_in[9];  const float* b2 = (const float*)d_in[10];
    const float* Wc = (const float*)d_in[11]; const float* bc = (const float*)d_in[12];

    const int N = in_sizes[4];
    const int E = in_sizes[1];
    const int C = in_sizes[12];            // 196
    const int B = out_size / C;            // 16
    (void)n_in; (void)ws_size;

    const int NB        = (N + BMASK) >> BSHIFT;              // dst buckets
    const int nchunk    = (E + ECHUNK - 1) / ECHUNK;          // build chunks
    const int nblk_pool = (N + POOL_CHUNK - 1) / POOL_CHUNK;
    const size_t PADDED = (size_t)NB * BCAP;                  // padded entries

    // ---- carve workspace ----
    char* w = (char*)d_ws;
    auto alloc = [&](size_t bytes) { void* p = (void*)w; w += WS_ALIGN(bytes); return p; };
    float* d_dinv    = (float*)alloc((size_t)N * 4);
    int*   d_rowbeg  = (int*)  alloc((size_t)N * 4);
    int*   d_rowend  = (int*)  alloc((size_t)N * 4);
    int*   d_bcursor = (int*)  alloc((size_t)NB * 4);
    int2*  d_cpair   = (int2*) alloc(PADDED * 8);
    float* d_hA      = (float*)alloc((size_t)N * 64 * 4);
    size_t tmp_bytes = (size_t)N * 64 * 4;
    if (PADDED * 8 > tmp_bytes) tmp_bytes = PADDED * 8;
    float* d_tmp     = (float*)alloc(tmp_bytes);
    float* d_partial = (float*)alloc((size_t)nblk_pool * B * 64 * 4);
    float* d_pool    = (float*)alloc((size_t)B * 64 * 4);
    int2*  d_sbuf    = (int2*)d_tmp;   // alias: staging dead before first gemm

    // ---- build CSR (padded buckets; no global histogram / scan) ----
    hipMemsetAsync(d_bcursor, 0, (size_t)NB * 4, stream);
    scatterD_kernel<<<nchunk, 512, NB * 4, stream>>>(esrc, edst, ea, E, NB,
                                                     d_bcursor, d_sbuf);
    bucketE1_kernel<<<NB, 256, 0, stream>>>(d_sbuf, d_bcursor, N, d_dinv,
                                            d_rowbeg, d_rowend);
    bucketE2_kernel<<<NB, 256, 0, stream>>>(d_sbuf, d_bcursor, d_dinv, N,
                                            d_rowbeg, d_cpair);

    const int nblk = (N + 3) / 4;
    const int gblk = (N + 255) / 256;
    // ---- layer 0 (K=128) ----
    gemm3_kernel<128><<<gblk, 256, 0, stream>>>(x, W0, d_tmp, N);
    spmm4_kernel<<<nblk, 256, 0, stream>>>(d_tmp, d_rowbeg, d_rowend, d_cpair,
                                           d_dinv, b0, d_hA, N);
    // ---- layer 1 (K=64) ----
    gemm3_kernel<64><<<gblk, 256, 0, stream>>>(d_hA, W1, d_tmp, N);
    spmm4_kernel<<<nblk, 256, 0, stream>>>(d_tmp, d_rowbeg, d_rowend, d_cpair,
                                           d_dinv, b1, d_hA, N);
    // ---- layer 2 (K=64) ----
    gemm3_kernel<64><<<gblk, 256, 0, stream>>>(d_hA, W2, d_tmp, N);
    spmm4_kernel<<<nblk, 256, 0, stream>>>(d_tmp, d_rowbeg, d_rowend, d_cpair,
                                           d_dinv, b2, d_hA, N);

    // ---- pool + classifier ----
    pool1_kernel<<<nblk_pool, 256, 0, stream>>>(d_hA, batch, N, B, d_partial);
    pool2_kernel<<<B, 256, 0, stream>>>(d_partial, nblk_pool, B, batch, N, d_pool);
    final_kernel<<<B, 256, 0, stream>>>(d_pool, Wc, bc, (float*)d_out, C);
}

// Round 16
// 624.329 us; speedup vs baseline: 6.5296x; 1.0075x over previous
//
#include <hip/hip_runtime.h>
#include <hip/hip_bf16.h>

// ---------------------------------------------------------------------------
// SGCN: 3 x [GEMM -> normalized SpMM (+self loop) -> bias+ReLU] -> mean pool
//       -> linear classifier.
// CSR built once (padded dst-buckets), reused 3 layers.
// R3: LDS-aggregated build (global atomics are memory-side RMWs on gfx950).
// R5: gemm thread=node, acc[64] in VGPRs, W broadcast from LDS.
// R6-R14: spmm study closed: full-sweep 4-acc unroll = 113.5us/389MB at the
//     L2-miss line rate (~3.75TB/s). Channel-split, src-tiling, GEMM-fusion,
//     cooperative co-phasing all measured and falsified (co-phase reached
//     the 180MB compulsory floor but at 164GB/s -- MLP collapse).
// R15: build tuning: 64-dst buckets (BSHIFT 6) double the per-(block,bucket)
//     write run (42->84B, halving partial-line amplification); scatterD
//     1024 threads (16 waves/block at 196 blocks). bucketE1/E2 on 64-dst
//     buckets (64-lane scan). BCAP 2432 = mean 2048 + 8.5 sigma.
// ---------------------------------------------------------------------------

#define WS_ALIGN(x) (((x) + 255) & ~(size_t)255)
#define POOL_CHUNK 128
#define ECHUNK 16384                   // edges per build block
#define BSHIFT 6                       // 64 dst nodes per bucket (R15)
#define BMASK  ((1 << BSHIFT) - 1)
#define SRCBITS 17                     // N=100000 < 2^17
#define BCAP 2432                      // bucket capacity (mean 2048 + 8.5s)

typedef float f32x4 __attribute__((ext_vector_type(4)));

// ---- build 1: scatter edges into padded bucket regions --------------------
__global__ __launch_bounds__(1024)
void scatterD_kernel(const int* __restrict__ src, const int* __restrict__ dst,
                     const float* __restrict__ ea, int E, int NB,
                     int* __restrict__ bcursor, int2* __restrict__ sbuf) {
    extern __shared__ int sh[];
    for (int i = threadIdx.x; i < NB; i += 1024) sh[i] = 0;
    __syncthreads();
    int beg = blockIdx.x * ECHUNK, end = min(beg + ECHUNK, E);
    for (int i = beg + threadIdx.x; i < end; i += 1024)
        atomicAdd(&sh[dst[i] >> BSHIFT], 1);
    __syncthreads();
    // one reserve atomic per (block, nonempty bucket) -> padded base position
    for (int i = threadIdx.x; i < NB; i += 1024) {
        int c = sh[i];
        sh[i] = c ? (i * BCAP + atomicAdd(&bcursor[i], c)) : 0;
    }
    __syncthreads();
    for (int i = beg + threadIdx.x; i < end; i += 1024) {
        int s = src[i], d = dst[i];
        int pos = atomicAdd(&sh[d >> BSHIFT], 1);        // LDS cursor
        sbuf[pos] = make_int2(s | ((d & BMASK) << SRCBITS),
                              __float_as_int(ea[i]));
    }
}

// ---- build 2: per-bucket degree count -> dinv, rowbeg/rowend --------------
__global__ __launch_bounds__(256)
void bucketE1_kernel(const int2* __restrict__ sbuf, const int* __restrict__ bcnt,
                     int N, float* __restrict__ dinv,
                     int* __restrict__ rowbeg, int* __restrict__ rowend) {
    __shared__ int dcount[64];
    if (threadIdx.x < 64) dcount[threadIdx.x] = 0;
    __syncthreads();
    int b = blockIdx.x;
    int base = b * BCAP, cnt = bcnt[b];
    for (int j = threadIdx.x; j < cnt; j += 256)
        atomicAdd(&dcount[(sbuf[base + j].x >> SRCBITS) & BMASK], 1);
    __syncthreads();
    if (threadIdx.x < 64) {                              // one full wave
        int c = dcount[threadIdx.x];
        int x = c;
        #pragma unroll
        for (int off = 1; off < 64; off <<= 1) {
            int t = __shfl_up(x, off);
            if (threadIdx.x >= off) x += t;
        }
        int d = (b << BSHIFT) + threadIdx.x;
        if (d < N) {
            int rb = base + x - c;                       // exclusive prefix
            rowbeg[d] = rb;
            rowend[d] = rb + c;
            dinv[d]   = 1.0f / sqrtf((float)(c + 1));    // +1 = self loop
        }
    }
}

// ---- build 3: within-bucket scatter to final CSR + coefficient ------------
__global__ __launch_bounds__(256)
void bucketE2_kernel(const int2* __restrict__ sbuf, const int* __restrict__ bcnt,
                     const float* __restrict__ dinv, int N,
                     const int* __restrict__ rowbeg, int2* __restrict__ cpair) {
    __shared__ int cur[64];
    __shared__ float sdinv[64];
    int b = blockIdx.x;
    int dbase = b << BSHIFT;
    if (threadIdx.x < 64) {
        int d = dbase + threadIdx.x;
        cur[threadIdx.x]   = (d < N) ? rowbeg[d] : 0;
        sdinv[threadIdx.x] = (d < N) ? dinv[d] : 0.f;
    }
    __syncthreads();
    int base = b * BCAP, cnt = bcnt[b];
    for (int j = threadIdx.x; j < cnt; j += 256) {
        int2 e = sbuf[base + j];
        int dl = (e.x >> SRCBITS) & BMASK;
        int s  = e.x & ((1 << SRCBITS) - 1);
        float c = dinv[s] * sdinv[dl] * expf(-__int_as_float(e.y));
        int pos = atomicAdd(&cur[dl], 1);                // LDS cursor
        cpair[pos] = make_int2(s, __float_as_int(c));
    }
}

// ---- dense GEMM: Y[N,64] = X[N,K] @ W[K,64] --------------------------------
// thread = node; acc[64] static in VGPRs; W broadcast from LDS (b128).
template <int K>
__global__ __launch_bounds__(256)
void gemm3_kernel(const float* __restrict__ X, const float* __restrict__ W,
                  float* __restrict__ Y, int N) {
    __shared__ float sW[K * 64];
    for (int i = threadIdx.x; i < K * 64; i += 256) sW[i] = W[i];
    __syncthreads();
    int node = blockIdx.x * 256 + threadIdx.x;
    if (node >= N) return;
    const float4* xr = reinterpret_cast<const float4*>(X + (size_t)node * K);
    float acc[64];
    #pragma unroll
    for (int c = 0; c < 64; ++c) acc[c] = 0.f;
    #pragma unroll 2
    for (int k4 = 0; k4 < K / 4; ++k4) {
        float4 xv = xr[k4];
        #pragma unroll
        for (int j = 0; j < 4; ++j) {
            float xs = (j == 0) ? xv.x : (j == 1) ? xv.y : (j == 2) ? xv.z : xv.w;
            const float4* wr =
                reinterpret_cast<const float4*>(sW + (k4 * 4 + j) * 64);
            #pragma unroll
            for (int c4 = 0; c4 < 16; ++c4) {
                float4 wv = wr[c4];
                acc[4 * c4 + 0] = fmaf(xs, wv.x, acc[4 * c4 + 0]);
                acc[4 * c4 + 1] = fmaf(xs, wv.y, acc[4 * c4 + 1]);
                acc[4 * c4 + 2] = fmaf(xs, wv.z, acc[4 * c4 + 2]);
                acc[4 * c4 + 3] = fmaf(xs, wv.w, acc[4 * c4 + 3]);
            }
        }
    }
    float4* yr = reinterpret_cast<float4*>(Y + (size_t)node * 64);
    #pragma unroll
    for (int c4 = 0; c4 < 16; ++c4)
        yr[c4] = make_float4(acc[4 * c4 + 0], acc[4 * c4 + 1],
                             acc[4 * c4 + 2], acc[4 * c4 + 3]);
}

// ---- SpMM common: one edge's contribution to a float4 of channels ---------
__device__ __forceinline__ void quad_acc(const int2* __restrict__ cpair,
                                         int eidx, const float* __restrict__ HW,
                                         int chb, float4& acc, bool ok) {
    long long pv = __builtin_nontemporal_load(
        reinterpret_cast<const long long*>(cpair) + eidx);
    int   s = (int)(pv & 0xffffffffLL);
    float c = __int_as_float((int)(pv >> 32));
    c = ok ? c : 0.f;
    const float4 hv = *reinterpret_cast<const float4*>(
        HW + (size_t)s * 64 + chb);
    acc.x = fmaf(c, hv.x, acc.x);
    acc.y = fmaf(c, hv.y, acc.y);
    acc.z = fmaf(c, hv.z, acc.z);
    acc.w = fmaf(c, hv.w, acc.w);
}

// ---- SpMM v4u: lane = (edge-slot 0..3, chan-quad 0..15); 4-acc unroll -----
__global__ __launch_bounds__(256)
void spmm4_kernel(const float* __restrict__ HW,
                  const int* __restrict__ rowbeg,
                  const int* __restrict__ rowend,
                  const int2* __restrict__ cpair,
                  const float* __restrict__ dinv,
                  const float* __restrict__ bias,
                  float* __restrict__ OUT, int N) {
    int node = blockIdx.x * 4 + (threadIdx.x >> 6);
    if (node >= N) return;
    int lane = threadIdx.x & 63;
    int g    = lane >> 4;              // edge slot
    int chb  = (lane & 15) * 4;        // channel base (float4)
    int beg = rowbeg[node], end = rowend[node];
    float di = dinv[node];

    float4 a0 = make_float4(0.f, 0.f, 0.f, 0.f);
    float4 a1 = make_float4(0.f, 0.f, 0.f, 0.f);
    float4 a2 = make_float4(0.f, 0.f, 0.f, 0.f);
    float4 a3 = make_float4(0.f, 0.f, 0.f, 0.f);
    float4 hs = *reinterpret_cast<const float4*>(HW + (size_t)node * 64 + chb);
    if (g == 0) {
        float s2 = di * di;
        a0 = make_float4(s2 * hs.x, s2 * hs.y, s2 * hs.z, s2 * hs.w);
    }

    int j = beg;
    for (; j + 16 <= end; j += 16) {
        quad_acc(cpair, j + g,      HW, chb, a0, true);
        quad_acc(cpair, j + 4 + g,  HW, chb, a1, true);
        quad_acc(cpair, j + 8 + g,  HW, chb, a2, true);
        quad_acc(cpair, j + 12 + g, HW, chb, a3, true);
    }
    for (; j + 8 <= end; j += 8) {
        quad_acc(cpair, j + g,     HW, chb, a0, true);
        quad_acc(cpair, j + 4 + g, HW, chb, a1, true);
    }
    for (; j < end; j += 4) {
        int e = j + g;
        bool ok = e < end;
        quad_acc(cpair, ok ? e : beg, HW, chb, a0, ok);
    }

    float4 r = make_float4((a0.x + a1.x) + (a2.x + a3.x),
                           (a0.y + a1.y) + (a2.y + a3.y),
                           (a0.z + a1.z) + (a2.z + a3.z),
                           (a0.w + a1.w) + (a2.w + a3.w));
    r.x += __shfl_xor(r.x, 32); r.y += __shfl_xor(r.y, 32);
    r.z += __shfl_xor(r.z, 32); r.w += __shfl_xor(r.w, 32);
    r.x += __shfl_xor(r.x, 16); r.y += __shfl_xor(r.y, 16);
    r.z += __shfl_xor(r.z, 16); r.w += __shfl_xor(r.w, 16);

    if (lane < 16) {
        float4 bv = *reinterpret_cast<const float4*>(bias + chb);
        f32x4 o;
        o.x = fmaxf(r.x + bv.x, 0.f);
        o.y = fmaxf(r.y + bv.y, 0.f);
        o.z = fmaxf(r.z + bv.z, 0.f);
        o.w = fmaxf(r.w + bv.w, 0.f);
        __builtin_nontemporal_store(o, reinterpret_cast<f32x4*>(
            OUT + (size_t)node * 64 + chb));
    }
}

// ---- pool stage 1: per-chunk per-graph partial sums -----------------------
__global__ __launch_bounds__(256)
void pool1_kernel(const float* __restrict__ H, const int* __restrict__ batch,
                  int N, int B, float* __restrict__ partial) {
    __shared__ float part[4][16][64];
    int lane = threadIdx.x & 63, wid = threadIdx.x >> 6;
    for (int g = 0; g < 16; ++g) part[wid][g][lane] = 0.f;
    int beg = blockIdx.x * POOL_CHUNK;
    int end = min(beg + POOL_CHUNK, N);
    float acc = 0.f; int cur = -1;
    for (int v = beg + wid; v < end; v += 4) {
        int g = batch[v];
        if (g != cur) {
            if (cur >= 0) part[wid][cur][lane] += acc;
            cur = g; acc = 0.f;
        }
        acc += H[(size_t)v * 64 + lane];
    }
    if (cur >= 0) part[wid][cur][lane] += acc;
    __syncthreads();
    float* outp = partial + (size_t)blockIdx.x * B * 64;
    for (int idx = threadIdx.x; idx < B * 64; idx += 256) {
        int g = idx >> 6, l = idx & 63;
        outp[idx] = part[0][g][l] + part[1][g][l] + part[2][g][l] + part[3][g][l];
    }
}

// ---- pool stage 2: fixed-order reduce over blocks, divide by count --------
__global__ __launch_bounds__(256)
void pool2_kernel(const float* __restrict__ partial, int nblk, int B,
                  const int* __restrict__ batch, int N,
                  float* __restrict__ pooled) {
    int g = blockIdx.x;
    int lane = threadIdx.x & 63, wid = threadIdx.x >> 6;
    float acc = 0.f;
    for (int b = wid; b < nblk; b += 4)
        acc += partial[(size_t)b * B * 64 + g * 64 + lane];
    __shared__ float sacc[4][64];
    sacc[wid][lane] = acc;
    __syncthreads();
    if (wid == 0) {
        int lo = 0, hi = N;
        while (lo < hi) { int m = (lo + hi) >> 1; if (batch[m] < g) lo = m + 1; else hi = m; }
        int s0 = lo;
        lo = 0; hi = N;
        while (lo < hi) { int m = (lo + hi) >> 1; if (batch[m] < g + 1) lo = m + 1; else hi = m; }
        float cnt = (float)(lo - s0);
        float s = sacc[0][lane] + sacc[1][lane] + sacc[2][lane] + sacc[3][lane];
        pooled[g * 64 + lane] = s / fmaxf(cnt, 1.0f);
    }
}

// ---- classifier: out[B,C] = pooled[B,64] @ Wc[64,C] + bc ------------------
__global__ __launch_bounds__(256)
void final_kernel(const float* __restrict__ pooled, const float* __restrict__ Wc,
                  const float* __restrict__ bc, float* __restrict__ out, int C) {
    int b = blockIdx.x;
    __shared__ float sp[64];
    if (threadIdx.x < 64) sp[threadIdx.x] = pooled[b * 64 + threadIdx.x];
    __syncthreads();
    for (int c = threadIdx.x; c < C; c += blockDim.x) {
        float acc = bc[c];
        #pragma unroll
        for (int k = 0; k < 64; ++k) acc = fmaf(sp[k], Wc[k * C + c], acc);
        out[b * C + c] = acc;
    }
}

extern "C" void kernel_launch(void* const* d_in, const int* in_sizes, int n_in,
                              void* d_out, int out_size, void* d_ws, size_t ws_size,
                              hipStream_t stream) {
    const float* x     = (const float*)d_in[0];
    const int*   esrc  = (const int*)  d_in[1];
    const int*   edst  = (const int*)  d_in[2];
    const float* ea    = (const float*)d_in[3];
    const int*   batch = (const int*)  d_in[4];
    const float* W0 = (const float*)d_in[5];  const float* b0 = (const float*)d_in[6];
    const float* W1 = (const float*)d_in[7];  const float* b1 = (const float*)d_in[8];
    const float* W2 = (const float*)d_in[9];  const float* b2 = (const float*)d_in[10];
    const float* Wc = (const float*)d_in[11]; const float* bc = (const float*)d_in[12];

    const int N = in_sizes[4];
    const int E = in_sizes[1];
    const int C = in_sizes[12];            // 196
    const int B = out_size / C;            // 16
    (void)n_in; (void)ws_size;

    const int NB        = (N + BMASK) >> BSHIFT;              // dst buckets
    const int nchunk    = (E + ECHUNK - 1) / ECHUNK;          // build chunks
    const int nblk_pool = (N + POOL_CHUNK - 1) / POOL_CHUNK;
    const size_t PADDED = (size_t)NB * BCAP;                  // padded entries

    // ---- carve workspace ----
    char* w = (char*)d_ws;
    auto alloc = [&](size_t bytes) { void* p = (void*)w; w += WS_ALIGN(bytes); return p; };
    float* d_dinv    = (float*)alloc((size_t)N * 4);
    int*   d_rowbeg  = (int*)  alloc((size_t)N * 4);
    int*   d_rowend  = (int*)  alloc((size_t)N * 4);
    int*   d_bcursor = (int*)  alloc((size_t)NB * 4);
    int2*  d_cpair   = (int2*) alloc(PADDED * 8);
    float* d_hA      = (float*)alloc((size_t)N * 64 * 4);
    size_t tmp_bytes = (size_t)N * 64 * 4;
    if (PADDED * 8 > tmp_bytes) tmp_bytes = PADDED * 8;
    float* d_tmp     = (float*)alloc(tmp_bytes);
    float* d_partial = (float*)alloc((size_t)nblk_pool * B * 64 * 4);
    float* d_pool    = (float*)alloc((size_t)B * 64 * 4);
    int2*  d_sbuf    = (int2*)d_tmp;   // alias: staging dead before first gemm

    // ---- build CSR (padded buckets; no global histogram / scan) ----
    hipMemsetAsync(d_bcursor, 0, (size_t)NB * 4, stream);
    scatterD_kernel<<<nchunk, 1024, NB * 4, stream>>>(esrc, edst, ea, E, NB,
                                                      d_bcursor, d_sbuf);
    bucketE1_kernel<<<NB, 256, 0, stream>>>(d_sbuf, d_bcursor, N, d_dinv,
                                            d_rowbeg, d_rowend);
    bucketE2_kernel<<<NB, 256, 0, stream>>>(d_sbuf, d_bcursor, d_dinv, N,
                                            d_rowbeg, d_cpair);

    const int nblk = (N + 3) / 4;
    const int gblk = (N + 255) / 256;
    // ---- layer 0 (K=128) ----
    gemm3_kernel<128><<<gblk, 256, 0, stream>>>(x, W0, d_tmp, N);
    spmm4_kernel<<<nblk, 256, 0, stream>>>(d_tmp, d_rowbeg, d_rowend, d_cpair,
                                           d_dinv, b0, d_hA, N);
    // ---- layer 1 (K=64) ----
    gemm3_kernel<64><<<gblk, 256, 0, stream>>>(d_hA, W1, d_tmp, N);
    spmm4_kernel<<<nblk, 256, 0, stream>>>(d_tmp, d_rowbeg, d_rowend, d_cpair,
                                           d_dinv, b1, d_hA, N);
    // ---- layer 2 (K=64) ----
    gemm3_kernel<64><<<gblk, 256, 0, stream>>>(d_hA, W2, d_tmp, N);
    spmm4_kernel<<<nblk, 256, 0, stream>>>(d_tmp, d_rowbeg, d_rowend, d_cpair,
                                           d_dinv, b2, d_hA, N);

    // ---- pool + classifier ----
    pool1_kernel<<<nblk_pool, 256, 0, stream>>>(d_hA, batch, N, B, d_partial);
    pool2_kernel<<<B, 256, 0, stream>>>(d_partial, nblk_pool, B, batch, N, d_pool);
    final_kernel<<<B, 256, 0, stream>>>(d_pool, Wc, bc, (float*)d_out, C);
}

// Round 17
// 614.499 us; speedup vs baseline: 6.6340x; 1.0160x over previous
//
#include <hip/hip_runtime.h>
#include <hip/hip_bf16.h>

// ---------------------------------------------------------------------------
// SGCN: 3 x [GEMM -> normalized SpMM (+self loop) -> bias+ReLU] -> mean pool
//       -> linear classifier.
// CSR built once (padded dst-buckets), reused 3 layers.
// R3: LDS-aggregated build (global atomics are memory-side RMWs on gfx950).
// R5: gemm thread=node, acc[64] in VGPRs, W broadcast from LDS.
// R6-R15: spmm study closed: 4-acc full-sweep = 113.5us/389MB at the random
//     64B-line fabric rate (~3.75TB/s). Channel-split, src-tiling, fusion,
//     cooperative co-phasing all measured and falsified. bf16 gather
//     rejected on numerics (threshold 1.8e-5).
// R16: (a) spmm 8-acc/32-edge unroll -- final MLP probe; (b) pool2+final
//     merged (block g reduces graph g's partials then emits out[g][:]).
// ---------------------------------------------------------------------------

#define WS_ALIGN(x) (((x) + 255) & ~(size_t)255)
#define POOL_CHUNK 128
#define ECHUNK 16384                   // edges per build block
#define BSHIFT 6                       // 64 dst nodes per bucket
#define BMASK  ((1 << BSHIFT) - 1)
#define SRCBITS 17                     // N=100000 < 2^17
#define BCAP 2432                      // bucket capacity (mean 2048 + 8.5s)

typedef float f32x4 __attribute__((ext_vector_type(4)));

// ---- build 1: scatter edges into padded bucket regions --------------------
__global__ __launch_bounds__(1024)
void scatterD_kernel(const int* __restrict__ src, const int* __restrict__ dst,
                     const float* __restrict__ ea, int E, int NB,
                     int* __restrict__ bcursor, int2* __restrict__ sbuf) {
    extern __shared__ int sh[];
    for (int i = threadIdx.x; i < NB; i += 1024) sh[i] = 0;
    __syncthreads();
    int beg = blockIdx.x * ECHUNK, end = min(beg + ECHUNK, E);
    for (int i = beg + threadIdx.x; i < end; i += 1024)
        atomicAdd(&sh[dst[i] >> BSHIFT], 1);
    __syncthreads();
    for (int i = threadIdx.x; i < NB; i += 1024) {
        int c = sh[i];
        sh[i] = c ? (i * BCAP + atomicAdd(&bcursor[i], c)) : 0;
    }
    __syncthreads();
    for (int i = beg + threadIdx.x; i < end; i += 1024) {
        int s = src[i], d = dst[i];
        int pos = atomicAdd(&sh[d >> BSHIFT], 1);        // LDS cursor
        sbuf[pos] = make_int2(s | ((d & BMASK) << SRCBITS),
                              __float_as_int(ea[i]));
    }
}

// ---- build 2: per-bucket degree count -> dinv, rowbeg/rowend --------------
__global__ __launch_bounds__(256)
void bucketE1_kernel(const int2* __restrict__ sbuf, const int* __restrict__ bcnt,
                     int N, float* __restrict__ dinv,
                     int* __restrict__ rowbeg, int* __restrict__ rowend) {
    __shared__ int dcount[64];
    if (threadIdx.x < 64) dcount[threadIdx.x] = 0;
    __syncthreads();
    int b = blockIdx.x;
    int base = b * BCAP, cnt = bcnt[b];
    for (int j = threadIdx.x; j < cnt; j += 256)
        atomicAdd(&dcount[(sbuf[base + j].x >> SRCBITS) & BMASK], 1);
    __syncthreads();
    if (threadIdx.x < 64) {                              // one full wave
        int c = dcount[threadIdx.x];
        int x = c;
        #pragma unroll
        for (int off = 1; off < 64; off <<= 1) {
            int t = __shfl_up(x, off);
            if (threadIdx.x >= off) x += t;
        }
        int d = (b << BSHIFT) + threadIdx.x;
        if (d < N) {
            int rb = base + x - c;                       // exclusive prefix
            rowbeg[d] = rb;
            rowend[d] = rb + c;
            dinv[d]   = 1.0f / sqrtf((float)(c + 1));    // +1 = self loop
        }
    }
}

// ---- build 3: within-bucket scatter to final CSR + coefficient ------------
__global__ __launch_bounds__(256)
void bucketE2_kernel(const int2* __restrict__ sbuf, const int* __restrict__ bcnt,
                     const float* __restrict__ dinv, int N,
                     const int* __restrict__ rowbeg, int2* __restrict__ cpair) {
    __shared__ int cur[64];
    __shared__ float sdinv[64];
    int b = blockIdx.x;
    int dbase = b << BSHIFT;
    if (threadIdx.x < 64) {
        int d = dbase + threadIdx.x;
        cur[threadIdx.x]   = (d < N) ? rowbeg[d] : 0;
        sdinv[threadIdx.x] = (d < N) ? dinv[d] : 0.f;
    }
    __syncthreads();
    int base = b * BCAP, cnt = bcnt[b];
    for (int j = threadIdx.x; j < cnt; j += 256) {
        int2 e = sbuf[base + j];
        int dl = (e.x >> SRCBITS) & BMASK;
        int s  = e.x & ((1 << SRCBITS) - 1);
        float c = dinv[s] * sdinv[dl] * expf(-__int_as_float(e.y));
        int pos = atomicAdd(&cur[dl], 1);                // LDS cursor
        cpair[pos] = make_int2(s, __float_as_int(c));
    }
}

// ---- dense GEMM: Y[N,64] = X[N,K] @ W[K,64] --------------------------------
template <int K>
__global__ __launch_bounds__(256)
void gemm3_kernel(const float* __restrict__ X, const float* __restrict__ W,
                  float* __restrict__ Y, int N) {
    __shared__ float sW[K * 64];
    for (int i = threadIdx.x; i < K * 64; i += 256) sW[i] = W[i];
    __syncthreads();
    int node = blockIdx.x * 256 + threadIdx.x;
    if (node >= N) return;
    const float4* xr = reinterpret_cast<const float4*>(X + (size_t)node * K);
    float acc[64];
    #pragma unroll
    for (int c = 0; c < 64; ++c) acc[c] = 0.f;
    #pragma unroll 2
    for (int k4 = 0; k4 < K / 4; ++k4) {
        float4 xv = xr[k4];
        #pragma unroll
        for (int j = 0; j < 4; ++j) {
            float xs = (j == 0) ? xv.x : (j == 1) ? xv.y : (j == 2) ? xv.z : xv.w;
            const float4* wr =
                reinterpret_cast<const float4*>(sW + (k4 * 4 + j) * 64);
            #pragma unroll
            for (int c4 = 0; c4 < 16; ++c4) {
                float4 wv = wr[c4];
                acc[4 * c4 + 0] = fmaf(xs, wv.x, acc[4 * c4 + 0]);
                acc[4 * c4 + 1] = fmaf(xs, wv.y, acc[4 * c4 + 1]);
                acc[4 * c4 + 2] = fmaf(xs, wv.z, acc[4 * c4 + 2]);
                acc[4 * c4 + 3] = fmaf(xs, wv.w, acc[4 * c4 + 3]);
            }
        }
    }
    float4* yr = reinterpret_cast<float4*>(Y + (size_t)node * 64);
    #pragma unroll
    for (int c4 = 0; c4 < 16; ++c4)
        yr[c4] = make_float4(acc[4 * c4 + 0], acc[4 * c4 + 1],
                             acc[4 * c4 + 2], acc[4 * c4 + 3]);
}

// ---- SpMM common: one edge's contribution to a float4 of channels ---------
__device__ __forceinline__ void quad_acc(const int2* __restrict__ cpair,
                                         int eidx, const float* __restrict__ HW,
                                         int chb, float4& acc, bool ok) {
    long long pv = __builtin_nontemporal_load(
        reinterpret_cast<const long long*>(cpair) + eidx);
    int   s = (int)(pv & 0xffffffffLL);
    float c = __int_as_float((int)(pv >> 32));
    c = ok ? c : 0.f;
    const float4 hv = *reinterpret_cast<const float4*>(
        HW + (size_t)s * 64 + chb);
    acc.x = fmaf(c, hv.x, acc.x);
    acc.y = fmaf(c, hv.y, acc.y);
    acc.z = fmaf(c, hv.z, acc.z);
    acc.w = fmaf(c, hv.w, acc.w);
}

// ---- SpMM v4u8: lane=(edge-slot 0..3, chan-quad 0..15); 8-acc unroll ------
// R16: 32 edges (8 independent vmem chains) in flight per wave.
__global__ __launch_bounds__(256)
void spmm4_kernel(const float* __restrict__ HW,
                  const int* __restrict__ rowbeg,
                  const int* __restrict__ rowend,
                  const int2* __restrict__ cpair,
                  const float* __restrict__ dinv,
                  const float* __restrict__ bias,
                  float* __restrict__ OUT, int N) {
    int node = blockIdx.x * 4 + (threadIdx.x >> 6);
    if (node >= N) return;
    int lane = threadIdx.x & 63;
    int g    = lane >> 4;              // edge slot
    int chb  = (lane & 15) * 4;        // channel base (float4)
    int beg = rowbeg[node], end = rowend[node];
    float di = dinv[node];

    float4 a0 = make_float4(0.f, 0.f, 0.f, 0.f);
    float4 a1 = make_float4(0.f, 0.f, 0.f, 0.f);
    float4 a2 = make_float4(0.f, 0.f, 0.f, 0.f);
    float4 a3 = make_float4(0.f, 0.f, 0.f, 0.f);
    float4 a4 = make_float4(0.f, 0.f, 0.f, 0.f);
    float4 a5 = make_float4(0.f, 0.f, 0.f, 0.f);
    float4 a6 = make_float4(0.f, 0.f, 0.f, 0.f);
    float4 a7 = make_float4(0.f, 0.f, 0.f, 0.f);
    float4 hs = *reinterpret_cast<const float4*>(HW + (size_t)node * 64 + chb);
    if (g == 0) {
        float s2 = di * di;
        a0 = make_float4(s2 * hs.x, s2 * hs.y, s2 * hs.z, s2 * hs.w);
    }

    int j = beg;
    for (; j + 32 <= end; j += 32) {
        quad_acc(cpair, j + g,      HW, chb, a0, true);
        quad_acc(cpair, j + 4 + g,  HW, chb, a1, true);
        quad_acc(cpair, j + 8 + g,  HW, chb, a2, true);
        quad_acc(cpair, j + 12 + g, HW, chb, a3, true);
        quad_acc(cpair, j + 16 + g, HW, chb, a4, true);
        quad_acc(cpair, j + 20 + g, HW, chb, a5, true);
        quad_acc(cpair, j + 24 + g, HW, chb, a6, true);
        quad_acc(cpair, j + 28 + g, HW, chb, a7, true);
    }
    for (; j + 16 <= end; j += 16) {
        quad_acc(cpair, j + g,      HW, chb, a0, true);
        quad_acc(cpair, j + 4 + g,  HW, chb, a1, true);
        quad_acc(cpair, j + 8 + g,  HW, chb, a2, true);
        quad_acc(cpair, j + 12 + g, HW, chb, a3, true);
    }
    for (; j + 8 <= end; j += 8) {
        quad_acc(cpair, j + g,     HW, chb, a0, true);
        quad_acc(cpair, j + 4 + g, HW, chb, a1, true);
    }
    for (; j < end; j += 4) {
        int e = j + g;
        bool ok = e < end;
        quad_acc(cpair, ok ? e : beg, HW, chb, a0, ok);
    }

    float4 r;
    r.x = ((a0.x + a1.x) + (a2.x + a3.x)) + ((a4.x + a5.x) + (a6.x + a7.x));
    r.y = ((a0.y + a1.y) + (a2.y + a3.y)) + ((a4.y + a5.y) + (a6.y + a7.y));
    r.z = ((a0.z + a1.z) + (a2.z + a3.z)) + ((a4.z + a5.z) + (a6.z + a7.z));
    r.w = ((a0.w + a1.w) + (a2.w + a3.w)) + ((a4.w + a5.w) + (a6.w + a7.w));
    r.x += __shfl_xor(r.x, 32); r.y += __shfl_xor(r.y, 32);
    r.z += __shfl_xor(r.z, 32); r.w += __shfl_xor(r.w, 32);
    r.x += __shfl_xor(r.x, 16); r.y += __shfl_xor(r.y, 16);
    r.z += __shfl_xor(r.z, 16); r.w += __shfl_xor(r.w, 16);

    if (lane < 16) {
        float4 bv = *reinterpret_cast<const float4*>(bias + chb);
        f32x4 o;
        o.x = fmaxf(r.x + bv.x, 0.f);
        o.y = fmaxf(r.y + bv.y, 0.f);
        o.z = fmaxf(r.z + bv.z, 0.f);
        o.w = fmaxf(r.w + bv.w, 0.f);
        __builtin_nontemporal_store(o, reinterpret_cast<f32x4*>(
            OUT + (size_t)node * 64 + chb));
    }
}

// ---- pool stage 1: per-chunk per-graph partial sums -----------------------
__global__ __launch_bounds__(256)
void pool1_kernel(const float* __restrict__ H, const int* __restrict__ batch,
                  int N, int B, float* __restrict__ partial) {
    __shared__ float part[4][16][64];
    int lane = threadIdx.x & 63, wid = threadIdx.x >> 6;
    for (int g = 0; g < 16; ++g) part[wid][g][lane] = 0.f;
    int beg = blockIdx.x * POOL_CHUNK;
    int end = min(beg + POOL_CHUNK, N);
    float acc = 0.f; int cur = -1;
    for (int v = beg + wid; v < end; v += 4) {
        int g = batch[v];
        if (g != cur) {
            if (cur >= 0) part[wid][cur][lane] += acc;
            cur = g; acc = 0.f;
        }
        acc += H[(size_t)v * 64 + lane];
    }
    if (cur >= 0) part[wid][cur][lane] += acc;
    __syncthreads();
    float* outp = partial + (size_t)blockIdx.x * B * 64;
    for (int idx = threadIdx.x; idx < B * 64; idx += 256) {
        int g = idx >> 6, l = idx & 63;
        outp[idx] = part[0][g][l] + part[1][g][l] + part[2][g][l] + part[3][g][l];
    }
}

// ---- pool stage 2 + classifier (R16 merged): block g -> out[g][0..C) ------
__global__ __launch_bounds__(256)
void pool2f_kernel(const float* __restrict__ partial, int nblk, int B,
                   const int* __restrict__ batch, int N,
                   const float* __restrict__ Wc, const float* __restrict__ bc,
                   float* __restrict__ out, int C) {
    int g = blockIdx.x;
    int lane = threadIdx.x & 63, wid = threadIdx.x >> 6;
    float acc = 0.f;
    for (int b = wid; b < nblk; b += 4)
        acc += partial[(size_t)b * B * 64 + g * 64 + lane];
    __shared__ float sacc[4][64];
    __shared__ float sp[64];
    sacc[wid][lane] = acc;
    __syncthreads();
    if (threadIdx.x < 64) {
        int lo = 0, hi = N;
        while (lo < hi) { int m = (lo + hi) >> 1; if (batch[m] < g) lo = m + 1; else hi = m; }
        int s0 = lo;
        lo = 0; hi = N;
        while (lo < hi) { int m = (lo + hi) >> 1; if (batch[m] < g + 1) lo = m + 1; else hi = m; }
        float cnt = (float)(lo - s0);
        float s = sacc[0][threadIdx.x] + sacc[1][threadIdx.x] +
                  sacc[2][threadIdx.x] + sacc[3][threadIdx.x];
        sp[threadIdx.x] = s / fmaxf(cnt, 1.0f);
    }
    __syncthreads();
    for (int c = threadIdx.x; c < C; c += 256) {
        float y = bc[c];
        #pragma unroll
        for (int k = 0; k < 64; ++k) y = fmaf(sp[k], Wc[k * C + c], y);
        out[g * C + c] = y;
    }
}

extern "C" void kernel_launch(void* const* d_in, const int* in_sizes, int n_in,
                              void* d_out, int out_size, void* d_ws, size_t ws_size,
                              hipStream_t stream) {
    const float* x     = (const float*)d_in[0];
    const int*   esrc  = (const int*)  d_in[1];
    const int*   edst  = (const int*)  d_in[2];
    const float* ea    = (const float*)d_in[3];
    const int*   batch = (const int*)  d_in[4];
    const float* W0 = (const float*)d_in[5];  const float* b0 = (const float*)d_in[6];
    const float* W1 = (const float*)d_in[7];  const float* b1 = (const float*)d_in[8];
    const float* W2 = (const float*)d_in[9];  const float* b2 = (const float*)d_in[10];
    const float* Wc = (const float*)d_in[11]; const float* bc = (const float*)d_in[12];

    const int N = in_sizes[4];
    const int E = in_sizes[1];
    const int C = in_sizes[12];            // 196
    const int B = out_size / C;            // 16
    (void)n_in; (void)ws_size;

    const int NB        = (N + BMASK) >> BSHIFT;              // dst buckets
    const int nchunk    = (E + ECHUNK - 1) / ECHUNK;          // build chunks
    const int nblk_pool = (N + POOL_CHUNK - 1) / POOL_CHUNK;
    const size_t PADDED = (size_t)NB * BCAP;                  // padded entries

    // ---- carve workspace ----
    char* w = (char*)d_ws;
    auto alloc = [&](size_t bytes) { void* p = (void*)w; w += WS_ALIGN(bytes); return p; };
    float* d_dinv    = (float*)alloc((size_t)N * 4);
    int*   d_rowbeg  = (int*)  alloc((size_t)N * 4);
    int*   d_rowend  = (int*)  alloc((size_t)N * 4);
    int*   d_bcursor = (int*)  alloc((size_t)NB * 4);
    int2*  d_cpair   = (int2*) alloc(PADDED * 8);
    float* d_hA      = (float*)alloc((size_t)N * 64 * 4);
    size_t tmp_bytes = (size_t)N * 64 * 4;
    if (PADDED * 8 > tmp_bytes) tmp_bytes = PADDED * 8;
    float* d_tmp     = (float*)alloc(tmp_bytes);
    float* d_partial = (float*)alloc((size_t)nblk_pool * B * 64 * 4);
    int2*  d_sbuf    = (int2*)d_tmp;   // alias: staging dead before first gemm

    // ---- build CSR (padded buckets; no global histogram / scan) ----
    hipMemsetAsync(d_bcursor, 0, (size_t)NB * 4, stream);
    scatterD_kernel<<<nchunk, 1024, NB * 4, stream>>>(esrc, edst, ea, E, NB,
                                                      d_bcursor, d_sbuf);
    bucketE1_kernel<<<NB, 256, 0, stream>>>(d_sbuf, d_bcursor, N, d_dinv,
                                            d_rowbeg, d_rowend);
    bucketE2_kernel<<<NB, 256, 0, stream>>>(d_sbuf, d_bcursor, d_dinv, N,
                                            d_rowbeg, d_cpair);

    const int nblk = (N + 3) / 4;
    const int gblk = (N + 255) / 256;
    // ---- layer 0 (K=128) ----
    gemm3_kernel<128><<<gblk, 256, 0, stream>>>(x, W0, d_tmp, N);
    spmm4_kernel<<<nblk, 256, 0, stream>>>(d_tmp, d_rowbeg, d_rowend, d_cpair,
                                           d_dinv, b0, d_hA, N);
    // ---- layer 1 (K=64) ----
    gemm3_kernel<64><<<gblk, 256, 0, stream>>>(d_hA, W1, d_tmp, N);
    spmm4_kernel<<<nblk, 256, 0, stream>>>(d_tmp, d_rowbeg, d_rowend, d_cpair,
                                           d_dinv, b1, d_hA, N);
    // ---- layer 2 (K=64) ----
    gemm3_kernel<64><<<gblk, 256, 0, stream>>>(d_hA, W2, d_tmp, N);
    spmm4_kernel<<<nblk, 256, 0, stream>>>(d_tmp, d_rowbeg, d_rowend, d_cpair,
                                           d_dinv, b2, d_hA, N);

    // ---- pool + classifier (merged stage 2) ----
    pool1_kernel<<<nblk_pool, 256, 0, stream>>>(d_hA, batch, N, B, d_partial);
    pool2f_kernel<<<B, 256, 0, stream>>>(d_partial, nblk_pool, B, batch, N,
                                         Wc, bc, (float*)d_out, C);
}

// Round 18
// 608.033 us; speedup vs baseline: 6.7046x; 1.0106x over previous
//
#include <hip/hip_runtime.h>
#include <hip/hip_bf16.h>

// ---------------------------------------------------------------------------
// SGCN: 3 x [GEMM -> normalized SpMM (+self loop) -> bias+ReLU] -> mean pool
//       -> linear classifier.
// FINAL (R17): best-of-each measured configuration.
//  - CSR build: LDS-aggregated, padded 64-dst buckets (R3/R7/R15).
//  - gemm: thread=node, acc[64] VGPR, W broadcast from LDS (R5).
//  - spmm: 4-acc/16-edge full-sweep (R14) -- measured optimum; 2-acc, 8-acc,
//    channel-split, src-tiling, GEMM-fusion, cooperative co-phasing all
//    measured worse (R6-R16). Pinned at random-gather line rate ~3.75TB/s.
//  - pool: two-stage, stage2 merged with classifier (R16).
// ---------------------------------------------------------------------------

#define WS_ALIGN(x) (((x) + 255) & ~(size_t)255)
#define POOL_CHUNK 128
#define ECHUNK 16384                   // edges per build block
#define BSHIFT 6                       // 64 dst nodes per bucket
#define BMASK  ((1 << BSHIFT) - 1)
#define SRCBITS 17                     // N=100000 < 2^17
#define BCAP 2432                      // bucket capacity (mean 2048 + 8.5s)

typedef float f32x4 __attribute__((ext_vector_type(4)));

// ---- build 1: scatter edges into padded bucket regions --------------------
__global__ __launch_bounds__(1024)
void scatterD_kernel(const int* __restrict__ src, const int* __restrict__ dst,
                     const float* __restrict__ ea, int E, int NB,
                     int* __restrict__ bcursor, int2* __restrict__ sbuf) {
    extern __shared__ int sh[];
    for (int i = threadIdx.x; i < NB; i += 1024) sh[i] = 0;
    __syncthreads();
    int beg = blockIdx.x * ECHUNK, end = min(beg + ECHUNK, E);
    for (int i = beg + threadIdx.x; i < end; i += 1024)
        atomicAdd(&sh[dst[i] >> BSHIFT], 1);
    __syncthreads();
    for (int i = threadIdx.x; i < NB; i += 1024) {
        int c = sh[i];
        sh[i] = c ? (i * BCAP + atomicAdd(&bcursor[i], c)) : 0;
    }
    __syncthreads();
    for (int i = beg + threadIdx.x; i < end; i += 1024) {
        int s = src[i], d = dst[i];
        int pos = atomicAdd(&sh[d >> BSHIFT], 1);        // LDS cursor
        sbuf[pos] = make_int2(s | ((d & BMASK) << SRCBITS),
                              __float_as_int(ea[i]));
    }
}

// ---- build 2: per-bucket degree count -> dinv, rowbeg/rowend --------------
__global__ __launch_bounds__(256)
void bucketE1_kernel(const int2* __restrict__ sbuf, const int* __restrict__ bcnt,
                     int N, float* __restrict__ dinv,
                     int* __restrict__ rowbeg, int* __restrict__ rowend) {
    __shared__ int dcount[64];
    if (threadIdx.x < 64) dcount[threadIdx.x] = 0;
    __syncthreads();
    int b = blockIdx.x;
    int base = b * BCAP, cnt = bcnt[b];
    for (int j = threadIdx.x; j < cnt; j += 256)
        atomicAdd(&dcount[(sbuf[base + j].x >> SRCBITS) & BMASK], 1);
    __syncthreads();
    if (threadIdx.x < 64) {                              // one full wave
        int c = dcount[threadIdx.x];
        int x = c;
        #pragma unroll
        for (int off = 1; off < 64; off <<= 1) {
            int t = __shfl_up(x, off);
            if (threadIdx.x >= off) x += t;
        }
        int d = (b << BSHIFT) + threadIdx.x;
        if (d < N) {
            int rb = base + x - c;                       // exclusive prefix
            rowbeg[d] = rb;
            rowend[d] = rb + c;
            dinv[d]   = 1.0f / sqrtf((float)(c + 1));    // +1 = self loop
        }
    }
}

// ---- build 3: within-bucket scatter to final CSR + coefficient ------------
__global__ __launch_bounds__(256)
void bucketE2_kernel(const int2* __restrict__ sbuf, const int* __restrict__ bcnt,
                     const float* __restrict__ dinv, int N,
                     const int* __restrict__ rowbeg, int2* __restrict__ cpair) {
    __shared__ int cur[64];
    __shared__ float sdinv[64];
    int b = blockIdx.x;
    int dbase = b << BSHIFT;
    if (threadIdx.x < 64) {
        int d = dbase + threadIdx.x;
        cur[threadIdx.x]   = (d < N) ? rowbeg[d] : 0;
        sdinv[threadIdx.x] = (d < N) ? dinv[d] : 0.f;
    }
    __syncthreads();
    int base = b * BCAP, cnt = bcnt[b];
    for (int j = threadIdx.x; j < cnt; j += 256) {
        int2 e = sbuf[base + j];
        int dl = (e.x >> SRCBITS) & BMASK;
        int s  = e.x & ((1 << SRCBITS) - 1);
        float c = dinv[s] * sdinv[dl] * expf(-__int_as_float(e.y));
        int pos = atomicAdd(&cur[dl], 1);                // LDS cursor
        cpair[pos] = make_int2(s, __float_as_int(c));
    }
}

// ---- dense GEMM: Y[N,64] = X[N,K] @ W[K,64] --------------------------------
template <int K>
__global__ __launch_bounds__(256)
void gemm3_kernel(const float* __restrict__ X, const float* __restrict__ W,
                  float* __restrict__ Y, int N) {
    __shared__ float sW[K * 64];
    for (int i = threadIdx.x; i < K * 64; i += 256) sW[i] = W[i];
    __syncthreads();
    int node = blockIdx.x * 256 + threadIdx.x;
    if (node >= N) return;
    const float4* xr = reinterpret_cast<const float4*>(X + (size_t)node * K);
    float acc[64];
    #pragma unroll
    for (int c = 0; c < 64; ++c) acc[c] = 0.f;
    #pragma unroll 2
    for (int k4 = 0; k4 < K / 4; ++k4) {
        float4 xv = xr[k4];
        #pragma unroll
        for (int j = 0; j < 4; ++j) {
            float xs = (j == 0) ? xv.x : (j == 1) ? xv.y : (j == 2) ? xv.z : xv.w;
            const float4* wr =
                reinterpret_cast<const float4*>(sW + (k4 * 4 + j) * 64);
            #pragma unroll
            for (int c4 = 0; c4 < 16; ++c4) {
                float4 wv = wr[c4];
                acc[4 * c4 + 0] = fmaf(xs, wv.x, acc[4 * c4 + 0]);
                acc[4 * c4 + 1] = fmaf(xs, wv.y, acc[4 * c4 + 1]);
                acc[4 * c4 + 2] = fmaf(xs, wv.z, acc[4 * c4 + 2]);
                acc[4 * c4 + 3] = fmaf(xs, wv.w, acc[4 * c4 + 3]);
            }
        }
    }
    float4* yr = reinterpret_cast<float4*>(Y + (size_t)node * 64);
    #pragma unroll
    for (int c4 = 0; c4 < 16; ++c4)
        yr[c4] = make_float4(acc[4 * c4 + 0], acc[4 * c4 + 1],
                             acc[4 * c4 + 2], acc[4 * c4 + 3]);
}

// ---- SpMM common: one edge's contribution to a float4 of channels ---------
__device__ __forceinline__ void quad_acc(const int2* __restrict__ cpair,
                                         int eidx, const float* __restrict__ HW,
                                         int chb, float4& acc, bool ok) {
    long long pv = __builtin_nontemporal_load(
        reinterpret_cast<const long long*>(cpair) + eidx);
    int   s = (int)(pv & 0xffffffffLL);
    float c = __int_as_float((int)(pv >> 32));
    c = ok ? c : 0.f;
    const float4 hv = *reinterpret_cast<const float4*>(
        HW + (size_t)s * 64 + chb);
    acc.x = fmaf(c, hv.x, acc.x);
    acc.y = fmaf(c, hv.y, acc.y);
    acc.z = fmaf(c, hv.z, acc.z);
    acc.w = fmaf(c, hv.w, acc.w);
}

// ---- SpMM v4u: lane = (edge-slot 0..3, chan-quad 0..15); 4-acc unroll -----
// Measured optimum (R14: 113.5us). 8-acc regressed (R16: VGPR 40, occ 58%).
__global__ __launch_bounds__(256)
void spmm4_kernel(const float* __restrict__ HW,
                  const int* __restrict__ rowbeg,
                  const int* __restrict__ rowend,
                  const int2* __restrict__ cpair,
                  const float* __restrict__ dinv,
                  const float* __restrict__ bias,
                  float* __restrict__ OUT, int N) {
    int node = blockIdx.x * 4 + (threadIdx.x >> 6);
    if (node >= N) return;
    int lane = threadIdx.x & 63;
    int g    = lane >> 4;              // edge slot
    int chb  = (lane & 15) * 4;        // channel base (float4)
    int beg = rowbeg[node], end = rowend[node];
    float di = dinv[node];

    float4 a0 = make_float4(0.f, 0.f, 0.f, 0.f);
    float4 a1 = make_float4(0.f, 0.f, 0.f, 0.f);
    float4 a2 = make_float4(0.f, 0.f, 0.f, 0.f);
    float4 a3 = make_float4(0.f, 0.f, 0.f, 0.f);
    float4 hs = *reinterpret_cast<const float4*>(HW + (size_t)node * 64 + chb);
    if (g == 0) {
        float s2 = di * di;
        a0 = make_float4(s2 * hs.x, s2 * hs.y, s2 * hs.z, s2 * hs.w);
    }

    int j = beg;
    for (; j + 16 <= end; j += 16) {
        quad_acc(cpair, j + g,      HW, chb, a0, true);
        quad_acc(cpair, j + 4 + g,  HW, chb, a1, true);
        quad_acc(cpair, j + 8 + g,  HW, chb, a2, true);
        quad_acc(cpair, j + 12 + g, HW, chb, a3, true);
    }
    for (; j + 8 <= end; j += 8) {
        quad_acc(cpair, j + g,     HW, chb, a0, true);
        quad_acc(cpair, j + 4 + g, HW, chb, a1, true);
    }
    for (; j < end; j += 4) {
        int e = j + g;
        bool ok = e < end;
        quad_acc(cpair, ok ? e : beg, HW, chb, a0, ok);
    }

    float4 r = make_float4((a0.x + a1.x) + (a2.x + a3.x),
                           (a0.y + a1.y) + (a2.y + a3.y),
                           (a0.z + a1.z) + (a2.z + a3.z),
                           (a0.w + a1.w) + (a2.w + a3.w));
    r.x += __shfl_xor(r.x, 32); r.y += __shfl_xor(r.y, 32);
    r.z += __shfl_xor(r.z, 32); r.w += __shfl_xor(r.w, 32);
    r.x += __shfl_xor(r.x, 16); r.y += __shfl_xor(r.y, 16);
    r.z += __shfl_xor(r.z, 16); r.w += __shfl_xor(r.w, 16);

    if (lane < 16) {
        float4 bv = *reinterpret_cast<const float4*>(bias + chb);
        f32x4 o;
        o.x = fmaxf(r.x + bv.x, 0.f);
        o.y = fmaxf(r.y + bv.y, 0.f);
        o.z = fmaxf(r.z + bv.z, 0.f);
        o.w = fmaxf(r.w + bv.w, 0.f);
        __builtin_nontemporal_store(o, reinterpret_cast<f32x4*>(
            OUT + (size_t)node * 64 + chb));
    }
}

// ---- pool stage 1: per-chunk per-graph partial sums -----------------------
__global__ __launch_bounds__(256)
void pool1_kernel(const float* __restrict__ H, const int* __restrict__ batch,
                  int N, int B, float* __restrict__ partial) {
    __shared__ float part[4][16][64];
    int lane = threadIdx.x & 63, wid = threadIdx.x >> 6;
    for (int g = 0; g < 16; ++g) part[wid][g][lane] = 0.f;
    int beg = blockIdx.x * POOL_CHUNK;
    int end = min(beg + POOL_CHUNK, N);
    float acc = 0.f; int cur = -1;
    for (int v = beg + wid; v < end; v += 4) {
        int g = batch[v];
        if (g != cur) {
            if (cur >= 0) part[wid][cur][lane] += acc;
            cur = g; acc = 0.f;
        }
        acc += H[(size_t)v * 64 + lane];
    }
    if (cur >= 0) part[wid][cur][lane] += acc;
    __syncthreads();
    float* outp = partial + (size_t)blockIdx.x * B * 64;
    for (int idx = threadIdx.x; idx < B * 64; idx += 256) {
        int g = idx >> 6, l = idx & 63;
        outp[idx] = part[0][g][l] + part[1][g][l] + part[2][g][l] + part[3][g][l];
    }
}

// ---- pool stage 2 + classifier (merged): block g -> out[g][0..C) ----------
__global__ __launch_bounds__(256)
void pool2f_kernel(const float* __restrict__ partial, int nblk, int B,
                   const int* __restrict__ batch, int N,
                   const float* __restrict__ Wc, const float* __restrict__ bc,
                   float* __restrict__ out, int C) {
    int g = blockIdx.x;
    int lane = threadIdx.x & 63, wid = threadIdx.x >> 6;
    float acc = 0.f;
    for (int b = wid; b < nblk; b += 4)
        acc += partial[(size_t)b * B * 64 + g * 64 + lane];
    __shared__ float sacc[4][64];
    __shared__ float sp[64];
    sacc[wid][lane] = acc;
    __syncthreads();
    if (threadIdx.x < 64) {
        int lo = 0, hi = N;
        while (lo < hi) { int m = (lo + hi) >> 1; if (batch[m] < g) lo = m + 1; else hi = m; }
        int s0 = lo;
        lo = 0; hi = N;
        while (lo < hi) { int m = (lo + hi) >> 1; if (batch[m] < g + 1) lo = m + 1; else hi = m; }
        float cnt = (float)(lo - s0);
        float s = sacc[0][threadIdx.x] + sacc[1][threadIdx.x] +
                  sacc[2][threadIdx.x] + sacc[3][threadIdx.x];
        sp[threadIdx.x] = s / fmaxf(cnt, 1.0f);
    }
    __syncthreads();
    for (int c = threadIdx.x; c < C; c += 256) {
        float y = bc[c];
        #pragma unroll
        for (int k = 0; k < 64; ++k) y = fmaf(sp[k], Wc[k * C + c], y);
        out[g * C + c] = y;
    }
}

extern "C" void kernel_launch(void* const* d_in, const int* in_sizes, int n_in,
                              void* d_out, int out_size, void* d_ws, size_t ws_size,
                              hipStream_t stream) {
    const float* x     = (const float*)d_in[0];
    const int*   esrc  = (const int*)  d_in[1];
    const int*   edst  = (const int*)  d_in[2];
    const float* ea    = (const float*)d_in[3];
    const int*   batch = (const int*)  d_in[4];
    const float* W0 = (const float*)d_in[5];  const float* b0 = (const float*)d_in[6];
    const float* W1 = (const float*)d_in[7];  const float* b1 = (const float*)d_in[8];
    const float* W2 = (const float*)d_in[9];  const float* b2 = (const float*)d_in[10];
    const float* Wc = (const float*)d_in[11]; const float* bc = (const float*)d_in[12];

    const int N = in_sizes[4];
    const int E = in_sizes[1];
    const int C = in_sizes[12];            // 196
    const int B = out_size / C;            // 16
    (void)n_in; (void)ws_size;

    const int NB        = (N + BMASK) >> BSHIFT;              // dst buckets
    const int nchunk    = (E + ECHUNK - 1) / ECHUNK;          // build chunks
    const int nblk_pool = (N + POOL_CHUNK - 1) / POOL_CHUNK;
    const size_t PADDED = (size_t)NB * BCAP;                  // padded entries

    // ---- carve workspace ----
    char* w = (char*)d_ws;
    auto alloc = [&](size_t bytes) { void* p = (void*)w; w += WS_ALIGN(bytes); return p; };
    float* d_dinv    = (float*)alloc((size_t)N * 4);
    int*   d_rowbeg  = (int*)  alloc((size_t)N * 4);
    int*   d_rowend  = (int*)  alloc((size_t)N * 4);
    int*   d_bcursor = (int*)  alloc((size_t)NB * 4);
    int2*  d_cpair   = (int2*) alloc(PADDED * 8);
    float* d_hA      = (float*)alloc((size_t)N * 64 * 4);
    size_t tmp_bytes = (size_t)N * 64 * 4;
    if (PADDED * 8 > tmp_bytes) tmp_bytes = PADDED * 8;
    float* d_tmp     = (float*)alloc(tmp_bytes);
    float* d_partial = (float*)alloc((size_t)nblk_pool * B * 64 * 4);
    int2*  d_sbuf    = (int2*)d_tmp;   // alias: staging dead before first gemm

    // ---- build CSR (padded buckets; no global histogram / scan) ----
    hipMemsetAsync(d_bcursor, 0, (size_t)NB * 4, stream);
    scatterD_kernel<<<nchunk, 1024, NB * 4, stream>>>(esrc, edst, ea, E, NB,
                                                      d_bcursor, d_sbuf);
    bucketE1_kernel<<<NB, 256, 0, stream>>>(d_sbuf, d_bcursor, N, d_dinv,
                                            d_rowbeg, d_rowend);
    bucketE2_kernel<<<NB, 256, 0, stream>>>(d_sbuf, d_bcursor, d_dinv, N,
                                            d_rowbeg, d_cpair);

    const int nblk = (N + 3) / 4;
    const int gblk = (N + 255) / 256;
    // ---- layer 0 (K=128) ----
    gemm3_kernel<128><<<gblk, 256, 0, stream>>>(x, W0, d_tmp, N);
    spmm4_kernel<<<nblk, 256, 0, stream>>>(d_tmp, d_rowbeg, d_rowend, d_cpair,
                                           d_dinv, b0, d_hA, N);
    // ---- layer 1 (K=64) ----
    gemm3_kernel<64><<<gblk, 256, 0, stream>>>(d_hA, W1, d_tmp, N);
    spmm4_kernel<<<nblk, 256, 0, stream>>>(d_tmp, d_rowbeg, d_rowend, d_cpair,
                                           d_dinv, b1, d_hA, N);
    // ---- layer 2 (K=64) ----
    gemm3_kernel<64><<<gblk, 256, 0, stream>>>(d_hA, W2, d_tmp, N);
    spmm4_kernel<<<nblk, 256, 0, stream>>>(d_tmp, d_rowbeg, d_rowend, d_cpair,
                                           d_dinv, b2, d_hA, N);

    // ---- pool + classifier (merged stage 2) ----
    pool1_kernel<<<nblk_pool, 256, 0, stream>>>(d_hA, batch, N, B, d_partial);
    pool2f_kernel<<<B, 256, 0, stream>>>(d_partial, nblk_pool, B, batch, N,
                                         Wc, bc, (float*)d_out, C);
}